// Round 1
// baseline (820.349 us; speedup 1.0000x reference)
//
#include <hip/hip_runtime.h>
#include <hip/hip_bf16.h>

// Problem dims (fixed by reference)
#define B_  2
#define LQ_ 1024
#define LK_ 10000
#define E_  256
#define H_  8
#define D_  32

// ---------------------------------------------------------------------------
// proj_gemm: C[M,256] = A[M,256] @ W[256,256] + bias[256]   (all f32)
// 128x128 tile, BK=8, 16x16 threads, 8x8 micro-tile per thread.
// ---------------------------------------------------------------------------
__global__ __launch_bounds__(256) void proj_gemm(const float* __restrict__ A,
                                                 const float* __restrict__ W,
                                                 const float* __restrict__ bias,
                                                 float* __restrict__ C, int M) {
  const int m0 = blockIdx.x * 128;
  const int n0 = blockIdx.y * 128;
  const int t  = threadIdx.x;
  const int tx = t & 15;   // col micro group -> cols tx*8 .. tx*8+7
  const int ty = t >> 4;   // row micro group -> rows ty*8 .. ty*8+7

  __shared__ __align__(16) float As[8][128];  // [k][m] (transposed)
  __shared__ __align__(16) float Ws[8][128];  // [k][n]

  float acc[8][8];
#pragma unroll
  for (int i = 0; i < 8; ++i)
#pragma unroll
    for (int j = 0; j < 8; ++j) acc[i][j] = 0.f;

  const int arow  = t >> 1;  // 0..127
  const int ahalf = t & 1;   // which 4-wide k chunk
  const int wk    = t >> 5;  // 0..7
  const int wc    = t & 31;  // 0..31 -> float4 col chunk

  for (int k0 = 0; k0 < 256; k0 += 8) {
    float4 av = make_float4(0.f, 0.f, 0.f, 0.f);
    if (m0 + arow < M)
      av = *(const float4*)&A[(size_t)(m0 + arow) * 256 + k0 + ahalf * 4];
    const float4 wv = *(const float4*)&W[(size_t)(k0 + wk) * 256 + n0 + wc * 4];
    __syncthreads();  // previous iteration's compute reads done
    As[ahalf * 4 + 0][arow] = av.x;
    As[ahalf * 4 + 1][arow] = av.y;
    As[ahalf * 4 + 2][arow] = av.z;
    As[ahalf * 4 + 3][arow] = av.w;
    *(float4*)&Ws[wk][wc * 4] = wv;
    __syncthreads();
#pragma unroll
    for (int kk = 0; kk < 8; ++kk) {
      float a[8], w[8];
      *(float4*)&a[0] = *(const float4*)&As[kk][ty * 8];
      *(float4*)&a[4] = *(const float4*)&As[kk][ty * 8 + 4];
      *(float4*)&w[0] = *(const float4*)&Ws[kk][tx * 8];
      *(float4*)&w[4] = *(const float4*)&Ws[kk][tx * 8 + 4];
#pragma unroll
      for (int i = 0; i < 8; ++i)
#pragma unroll
        for (int j = 0; j < 8; ++j) acc[i][j] = fmaf(a[i], w[j], acc[i][j]);
    }
  }

#pragma unroll
  for (int i = 0; i < 8; ++i) {
    const int row = m0 + ty * 8 + i;
    if (row < M) {
      const float* bptr = &bias[n0 + tx * 8];
      float4 o0, o1;
      o0.x = acc[i][0] + bptr[0];
      o0.y = acc[i][1] + bptr[1];
      o0.z = acc[i][2] + bptr[2];
      o0.w = acc[i][3] + bptr[3];
      o1.x = acc[i][4] + bptr[4];
      o1.y = acc[i][5] + bptr[5];
      o1.z = acc[i][6] + bptr[6];
      o1.w = acc[i][7] + bptr[7];
      *(float4*)&C[(size_t)row * 256 + n0 + tx * 8]     = o0;
      *(float4*)&C[(size_t)row * 256 + n0 + tx * 8 + 4] = o1;
    }
  }
}

// ---------------------------------------------------------------------------
// flash_attn_f32: per (b,h, 32 q-rows) block; online softmax over 64-wide
// K tiles; all f32. q/k/v are projected tensors [B*L, 256], head h = cols
// h*32..h*32+31. o gets (attn @ v), softmax-normalized.
// ---------------------------------------------------------------------------
#define DOT4(acc, a, bb) \
  acc = fmaf((a).x, (bb).x, fmaf((a).y, (bb).y, fmaf((a).z, (bb).z, fmaf((a).w, (bb).w, acc))))

__global__ __launch_bounds__(256) void flash_attn_f32(const float* __restrict__ q,
                                                      const float* __restrict__ k,
                                                      const float* __restrict__ v,
                                                      float* __restrict__ o) {
  const int qb = blockIdx.x;  // 0..31 (q tile of 32 rows)
  const int h  = blockIdx.y;  // 0..7
  const int b  = blockIdx.z;  // 0..1
  const int t  = threadIdx.x;

  __shared__ __align__(16) float Qs[32][36];  // +4 pad (keeps float4 align, breaks stride-32)
  __shared__ __align__(16) float Ks[64][36];
  __shared__ __align__(16) float Vs[64][36];
  __shared__ __align__(16) float Ss[32][65];  // +1 pad (scalar access)

  // row-group ownership: 8 threads per q-row (consecutive lanes, same wave)
  const int r  = t >> 3;       // 0..31 q row
  const int g  = t & 7;        // 0..7
  const int j0 = g * 8;        // softmax col slice [j0, j0+8)
  const int c0 = g * 4;        // PV / load col slice [c0, c0+4)

  // QK micro mapping: 2 rows x 4 cols per thread
  const int tq = t & 15;       // rows tq*2, tq*2+1
  const int tk = t >> 4;       // cols tk*4 .. tk*4+3

  // load Q tile (32x32): one float4 per thread
  *(float4*)&Qs[r][c0] =
      *(const float4*)&q[((size_t)(b * LQ_ + qb * 32 + r)) * E_ + h * D_ + c0];

  float m_run = -1e30f;
  float l_run = 0.f;
  float accO[4] = {0.f, 0.f, 0.f, 0.f};

  const size_t kvbase = (size_t)b * LK_ * E_ + (size_t)h * D_;

  const int NT = (LK_ + 63) / 64;  // 157 (last tile: 16 valid rows)
  for (int kt = 0; kt < NT; ++kt) {
    const int kv0 = kt * 64;
    __syncthreads();  // previous tile's Ks/Vs/Ss reads done (also covers Qs load once)
    // load K/V tile (64x32 each): two float4 per thread; stale rows masked later
    if (kv0 + r < LK_) {
      *(float4*)&Ks[r][c0] = *(const float4*)&k[kvbase + (size_t)(kv0 + r) * E_ + c0];
      *(float4*)&Vs[r][c0] = *(const float4*)&v[kvbase + (size_t)(kv0 + r) * E_ + c0];
    }
    if (kv0 + 32 + r < LK_) {
      *(float4*)&Ks[32 + r][c0] = *(const float4*)&k[kvbase + (size_t)(kv0 + 32 + r) * E_ + c0];
      *(float4*)&Vs[32 + r][c0] = *(const float4*)&v[kvbase + (size_t)(kv0 + 32 + r) * E_ + c0];
    }
    __syncthreads();

    // S = Q @ K^T  (32x64 tile, 2x4 micro per thread)
    float s00 = 0.f, s01 = 0.f, s02 = 0.f, s03 = 0.f;
    float s10 = 0.f, s11 = 0.f, s12 = 0.f, s13 = 0.f;
#pragma unroll
    for (int d4 = 0; d4 < 8; ++d4) {
      const float4 q0 = *(const float4*)&Qs[tq * 2 + 0][d4 * 4];
      const float4 q1 = *(const float4*)&Qs[tq * 2 + 1][d4 * 4];
      const float4 k0 = *(const float4*)&Ks[tk * 4 + 0][d4 * 4];
      const float4 k1 = *(const float4*)&Ks[tk * 4 + 1][d4 * 4];
      const float4 k2 = *(const float4*)&Ks[tk * 4 + 2][d4 * 4];
      const float4 k3 = *(const float4*)&Ks[tk * 4 + 3][d4 * 4];
      DOT4(s00, q0, k0); DOT4(s01, q0, k1); DOT4(s02, q0, k2); DOT4(s03, q0, k3);
      DOT4(s10, q1, k0); DOT4(s11, q1, k1); DOT4(s12, q1, k2); DOT4(s13, q1, k3);
    }
    Ss[tq * 2 + 0][tk * 4 + 0] = s00;
    Ss[tq * 2 + 0][tk * 4 + 1] = s01;
    Ss[tq * 2 + 0][tk * 4 + 2] = s02;
    Ss[tq * 2 + 0][tk * 4 + 3] = s03;
    Ss[tq * 2 + 1][tk * 4 + 0] = s10;
    Ss[tq * 2 + 1][tk * 4 + 1] = s11;
    Ss[tq * 2 + 1][tk * 4 + 2] = s12;
    Ss[tq * 2 + 1][tk * 4 + 3] = s13;
    __syncthreads();

    // online softmax: 8 lanes per row, each owns 8 cols; m/l replicated in regs
    float sv[8];
    float pm = -1e30f;
#pragma unroll
    for (int jj = 0; jj < 8; ++jj) {
      sv[jj] = Ss[r][j0 + jj];
      if (kv0 + j0 + jj < LK_) pm = fmaxf(pm, sv[jj]);
    }
    pm = fmaxf(pm, __shfl_xor(pm, 1));
    pm = fmaxf(pm, __shfl_xor(pm, 2));
    pm = fmaxf(pm, __shfl_xor(pm, 4));
    const float mnew   = fmaxf(m_run, pm);
    const float fscale = __expf(m_run - mnew);  // first tile: exp(-huge)=0
    float psum = 0.f;
#pragma unroll
    for (int jj = 0; jj < 8; ++jj) {
      const float p = (kv0 + j0 + jj < LK_) ? __expf(sv[jj] - mnew) : 0.f;
      Ss[r][j0 + jj] = p;
      psum += p;
    }
    psum += __shfl_xor(psum, 1);
    psum += __shfl_xor(psum, 2);
    psum += __shfl_xor(psum, 4);
    m_run = mnew;
    l_run = l_run * fscale + psum;
    __syncthreads();

    // O = O*fscale + P @ V  (each thread: row r, cols c0..c0+3)
    accO[0] *= fscale; accO[1] *= fscale; accO[2] *= fscale; accO[3] *= fscale;
#pragma unroll 8
    for (int j = 0; j < 64; ++j) {
      const float  p  = Ss[r][j];
      const float4 vv = *(const float4*)&Vs[j][c0];
      accO[0] = fmaf(p, vv.x, accO[0]);
      accO[1] = fmaf(p, vv.y, accO[1]);
      accO[2] = fmaf(p, vv.z, accO[2]);
      accO[3] = fmaf(p, vv.w, accO[3]);
    }
  }

  const float inv = 1.f / l_run;
  float4 ov;
  ov.x = accO[0] * inv;
  ov.y = accO[1] * inv;
  ov.z = accO[2] * inv;
  ov.w = accO[3] * inv;
  *(float4*)&o[((size_t)(b * LQ_ + qb * 32 + r)) * E_ + h * D_ + c0] = ov;
}

// ---------------------------------------------------------------------------
extern "C" void kernel_launch(void* const* d_in, const int* in_sizes, int n_in,
                              void* d_out, int out_size, void* d_ws, size_t ws_size,
                              hipStream_t stream) {
  const float* bev     = (const float*)d_in[0];
  const float* queries = (const float*)d_in[1];
  const float* Wq      = (const float*)d_in[2];
  const float* bq      = (const float*)d_in[3];
  const float* Wk      = (const float*)d_in[4];
  const float* bk      = (const float*)d_in[5];
  const float* Wv      = (const float*)d_in[6];
  const float* bv      = (const float*)d_in[7];
  const float* Wo      = (const float*)d_in[8];
  const float* bo      = (const float*)d_in[9];
  float* out = (float*)d_out;

  // workspace layout (f32): q | k | v | o  -> ~45.2 MB total
  float* qws = (float*)d_ws;
  float* kws = qws + (size_t)B_ * LQ_ * E_;  // +524288
  float* vws = kws + (size_t)B_ * LK_ * E_;  // +5120000
  float* ows = vws + (size_t)B_ * LK_ * E_;  // +5120000

  const int MQ = B_ * LQ_;  // 2048
  const int MK = B_ * LK_;  // 20000

  proj_gemm<<<dim3(16, 2), 256, 0, stream>>>(queries, Wq, bq, qws, MQ);
  proj_gemm<<<dim3(157, 2), 256, 0, stream>>>(bev, Wk, bk, kws, MK);
  proj_gemm<<<dim3(157, 2), 256, 0, stream>>>(bev, Wv, bv, vws, MK);
  flash_attn_f32<<<dim3(LQ_ / 32, H_, B_), 256, 0, stream>>>(qws, kws, vws, ows);
  proj_gemm<<<dim3(16, 2), 256, 0, stream>>>(ows, Wo, bo, out, MQ);
}

// Round 2
// 687.884 us; speedup vs baseline: 1.1926x; 1.1926x over previous
//
#include <hip/hip_runtime.h>
#include <hip/hip_bf16.h>

// Problem dims (fixed by reference)
#define B_  2
#define LQ_ 1024
#define LK_ 10000
#define E_  256
#define H_  8
#define D_  32

// ---------------------------------------------------------------------------
// proj_gemm: C[M,256] = A[M,256] @ W[256,256] + bias[256]   (all f32)
// 128x128 tile, BK=8, 16x16 threads, 8x8 micro-tile per thread.
// ---------------------------------------------------------------------------
__global__ __launch_bounds__(256) void proj_gemm(const float* __restrict__ A,
                                                 const float* __restrict__ W,
                                                 const float* __restrict__ bias,
                                                 float* __restrict__ C, int M) {
  const int m0 = blockIdx.x * 128;
  const int n0 = blockIdx.y * 128;
  const int t  = threadIdx.x;
  const int tx = t & 15;   // col micro group -> cols tx*8 .. tx*8+7
  const int ty = t >> 4;   // row micro group -> rows ty*8 .. ty*8+7

  __shared__ __align__(16) float As[8][128];  // [k][m] (transposed)
  __shared__ __align__(16) float Ws[8][128];  // [k][n]

  float acc[8][8];
#pragma unroll
  for (int i = 0; i < 8; ++i)
#pragma unroll
    for (int j = 0; j < 8; ++j) acc[i][j] = 0.f;

  const int arow  = t >> 1;  // 0..127
  const int ahalf = t & 1;   // which 4-wide k chunk
  const int wk    = t >> 5;  // 0..7
  const int wc    = t & 31;  // 0..31 -> float4 col chunk

  for (int k0 = 0; k0 < 256; k0 += 8) {
    float4 av = make_float4(0.f, 0.f, 0.f, 0.f);
    if (m0 + arow < M)
      av = *(const float4*)&A[(size_t)(m0 + arow) * 256 + k0 + ahalf * 4];
    const float4 wv = *(const float4*)&W[(size_t)(k0 + wk) * 256 + n0 + wc * 4];
    __syncthreads();  // previous iteration's compute reads done
    As[ahalf * 4 + 0][arow] = av.x;
    As[ahalf * 4 + 1][arow] = av.y;
    As[ahalf * 4 + 2][arow] = av.z;
    As[ahalf * 4 + 3][arow] = av.w;
    *(float4*)&Ws[wk][wc * 4] = wv;
    __syncthreads();
#pragma unroll
    for (int kk = 0; kk < 8; ++kk) {
      float a[8], w[8];
      *(float4*)&a[0] = *(const float4*)&As[kk][ty * 8];
      *(float4*)&a[4] = *(const float4*)&As[kk][ty * 8 + 4];
      *(float4*)&w[0] = *(const float4*)&Ws[kk][tx * 8];
      *(float4*)&w[4] = *(const float4*)&Ws[kk][tx * 8 + 4];
#pragma unroll
      for (int i = 0; i < 8; ++i)
#pragma unroll
        for (int j = 0; j < 8; ++j) acc[i][j] = fmaf(a[i], w[j], acc[i][j]);
    }
  }

#pragma unroll
  for (int i = 0; i < 8; ++i) {
    const int row = m0 + ty * 8 + i;
    if (row < M) {
      const float* bptr = &bias[n0 + tx * 8];
      float4 o0, o1;
      o0.x = acc[i][0] + bptr[0];
      o0.y = acc[i][1] + bptr[1];
      o0.z = acc[i][2] + bptr[2];
      o0.w = acc[i][3] + bptr[3];
      o1.x = acc[i][4] + bptr[4];
      o1.y = acc[i][5] + bptr[5];
      o1.z = acc[i][6] + bptr[6];
      o1.w = acc[i][7] + bptr[7];
      *(float4*)&C[(size_t)row * 256 + n0 + tx * 8]     = o0;
      *(float4*)&C[(size_t)row * 256 + n0 + tx * 8 + 4] = o1;
    }
  }
}

// ---------------------------------------------------------------------------
// flash_attn_f32 (split-KV): per (qb, h, z=s*B+b) block; handles KV tiles
// [t0, t1). Writes unnormalized partial O + running (m,l) to workspace
// (or normalized directly to o_direct when direct != 0).
// ---------------------------------------------------------------------------
#define DOT4(acc, a, bb) \
  acc = fmaf((a).x, (bb).x, fmaf((a).y, (bb).y, fmaf((a).z, (bb).z, fmaf((a).w, (bb).w, acc))))

__global__ __launch_bounds__(256) void flash_attn_f32(const float* __restrict__ q,
                                                      const float* __restrict__ k,
                                                      const float* __restrict__ v,
                                                      float* __restrict__ Opart,
                                                      float* __restrict__ mpart,
                                                      float* __restrict__ lpart,
                                                      float* __restrict__ o_direct,
                                                      int tiles_per_split, int direct) {
  const int qb = blockIdx.x;            // 0..31 (q tile of 32 rows)
  const int h  = blockIdx.y;            // 0..7
  const int z  = blockIdx.z;            // s*B + b
  const int s  = z / B_;
  const int b  = z % B_;
  const int t  = threadIdx.x;

  const int NT = (LK_ + 63) / 64;       // 157
  const int t0 = s * tiles_per_split;
  const int t1 = min(NT, t0 + tiles_per_split);

  __shared__ __align__(16) float Qs[32][36];
  __shared__ __align__(16) float Ks[64][36];
  __shared__ __align__(16) float Vs[64][36];
  __shared__ __align__(16) float Ss[32][65];

  // row-group ownership: 8 threads per q-row (consecutive lanes, same wave)
  const int r  = t >> 3;       // 0..31 q row
  const int g  = t & 7;        // 0..7
  const int j0 = g * 8;        // softmax col slice [j0, j0+8)
  const int c0 = g * 4;        // PV / load col slice [c0, c0+4)

  // QK micro mapping: 2 rows x 4 cols per thread
  const int tq = t & 15;       // rows tq*2, tq*2+1
  const int tk = t >> 4;       // cols tk*4 .. tk*4+3

  // load Q tile (32x32): one float4 per thread
  *(float4*)&Qs[r][c0] =
      *(const float4*)&q[((size_t)(b * LQ_ + qb * 32 + r)) * E_ + h * D_ + c0];

  float m_run = -1e30f;
  float l_run = 0.f;
  float accO[4] = {0.f, 0.f, 0.f, 0.f};

  const size_t kvbase = (size_t)b * LK_ * E_ + (size_t)h * D_;

  for (int kt = t0; kt < t1; ++kt) {
    const int kv0 = kt * 64;
    __syncthreads();  // previous tile's Ks/Vs/Ss reads done (also covers Qs load once)
    if (kv0 + r < LK_) {
      *(float4*)&Ks[r][c0] = *(const float4*)&k[kvbase + (size_t)(kv0 + r) * E_ + c0];
      *(float4*)&Vs[r][c0] = *(const float4*)&v[kvbase + (size_t)(kv0 + r) * E_ + c0];
    }
    if (kv0 + 32 + r < LK_) {
      *(float4*)&Ks[32 + r][c0] = *(const float4*)&k[kvbase + (size_t)(kv0 + 32 + r) * E_ + c0];
      *(float4*)&Vs[32 + r][c0] = *(const float4*)&v[kvbase + (size_t)(kv0 + 32 + r) * E_ + c0];
    }
    __syncthreads();

    // S = Q @ K^T  (32x64 tile, 2x4 micro per thread)
    float s00 = 0.f, s01 = 0.f, s02 = 0.f, s03 = 0.f;
    float s10 = 0.f, s11 = 0.f, s12 = 0.f, s13 = 0.f;
#pragma unroll
    for (int d4 = 0; d4 < 8; ++d4) {
      const float4 q0 = *(const float4*)&Qs[tq * 2 + 0][d4 * 4];
      const float4 q1 = *(const float4*)&Qs[tq * 2 + 1][d4 * 4];
      const float4 k0 = *(const float4*)&Ks[tk * 4 + 0][d4 * 4];
      const float4 k1 = *(const float4*)&Ks[tk * 4 + 1][d4 * 4];
      const float4 k2 = *(const float4*)&Ks[tk * 4 + 2][d4 * 4];
      const float4 k3 = *(const float4*)&Ks[tk * 4 + 3][d4 * 4];
      DOT4(s00, q0, k0); DOT4(s01, q0, k1); DOT4(s02, q0, k2); DOT4(s03, q0, k3);
      DOT4(s10, q1, k0); DOT4(s11, q1, k1); DOT4(s12, q1, k2); DOT4(s13, q1, k3);
    }
    Ss[tq * 2 + 0][tk * 4 + 0] = s00;
    Ss[tq * 2 + 0][tk * 4 + 1] = s01;
    Ss[tq * 2 + 0][tk * 4 + 2] = s02;
    Ss[tq * 2 + 0][tk * 4 + 3] = s03;
    Ss[tq * 2 + 1][tk * 4 + 0] = s10;
    Ss[tq * 2 + 1][tk * 4 + 1] = s11;
    Ss[tq * 2 + 1][tk * 4 + 2] = s12;
    Ss[tq * 2 + 1][tk * 4 + 3] = s13;
    __syncthreads();

    // online softmax: 8 lanes per row, each owns 8 cols; m/l replicated in regs
    float sv[8];
    float pm = -1e30f;
#pragma unroll
    for (int jj = 0; jj < 8; ++jj) {
      sv[jj] = Ss[r][j0 + jj];
      if (kv0 + j0 + jj < LK_) pm = fmaxf(pm, sv[jj]);
    }
    pm = fmaxf(pm, __shfl_xor(pm, 1));
    pm = fmaxf(pm, __shfl_xor(pm, 2));
    pm = fmaxf(pm, __shfl_xor(pm, 4));
    const float mnew   = fmaxf(m_run, pm);
    const float fscale = __expf(m_run - mnew);  // first tile: exp(-huge)=0
    float psum = 0.f;
#pragma unroll
    for (int jj = 0; jj < 8; ++jj) {
      const float p = (kv0 + j0 + jj < LK_) ? __expf(sv[jj] - mnew) : 0.f;
      Ss[r][j0 + jj] = p;
      psum += p;
    }
    psum += __shfl_xor(psum, 1);
    psum += __shfl_xor(psum, 2);
    psum += __shfl_xor(psum, 4);
    m_run = mnew;
    l_run = l_run * fscale + psum;
    __syncthreads();

    // O = O*fscale + P @ V  (each thread: row r, cols c0..c0+3)
    accO[0] *= fscale; accO[1] *= fscale; accO[2] *= fscale; accO[3] *= fscale;
#pragma unroll 8
    for (int j = 0; j < 64; ++j) {
      const float  p  = Ss[r][j];
      const float4 vv = *(const float4*)&Vs[j][c0];
      accO[0] = fmaf(p, vv.x, accO[0]);
      accO[1] = fmaf(p, vv.y, accO[1]);
      accO[2] = fmaf(p, vv.z, accO[2]);
      accO[3] = fmaf(p, vv.w, accO[3]);
    }
  }

  if (direct) {
    const float inv = 1.f / l_run;
    float4 ov;
    ov.x = accO[0] * inv;
    ov.y = accO[1] * inv;
    ov.z = accO[2] * inv;
    ov.w = accO[3] * inv;
    *(float4*)&o_direct[((size_t)(b * LQ_ + qb * 32 + r)) * E_ + h * D_ + c0] = ov;
  } else {
    const size_t pbase =
        (size_t)s * (B_ * H_ * LQ_) + ((size_t)b * H_ + h) * LQ_ + qb * 32 + r;
    float4 ov = make_float4(accO[0], accO[1], accO[2], accO[3]);
    *(float4*)&Opart[pbase * D_ + c0] = ov;
    if (g == 0) {
      mpart[pbase] = m_run;
      lpart[pbase] = l_run;
    }
  }
}

// ---------------------------------------------------------------------------
// attn_merge: combine split partials -> normalized o [B*LQ, E]
// ---------------------------------------------------------------------------
__global__ __launch_bounds__(256) void attn_merge(const float* __restrict__ Opart,
                                                  const float* __restrict__ mpart,
                                                  const float* __restrict__ lpart,
                                                  float* __restrict__ o, int S) {
  const int idx = blockIdx.x * 256 + threadIdx.x;  // over B*LQ*E
  if (idx >= B_ * LQ_ * E_) return;
  const int e   = idx & (E_ - 1);
  const int row = idx >> 8;       // b*LQ + q
  const int b   = row >> 10;      // LQ = 1024
  const int qq  = row & (LQ_ - 1);
  const int h   = e >> 5;
  const int d   = e & (D_ - 1);
  const size_t base = ((size_t)b * H_ + h) * LQ_ + qq;
  const size_t stride = (size_t)B_ * H_ * LQ_;

  float mmax = -1e30f;
  for (int s = 0; s < S; ++s) mmax = fmaxf(mmax, mpart[s * stride + base]);
  float lsum = 0.f, osum = 0.f;
  for (int s = 0; s < S; ++s) {
    const float w = __expf(mpart[s * stride + base] - mmax);
    lsum += w * lpart[s * stride + base];
    osum += w * Opart[(s * stride + base) * D_ + d];
  }
  o[idx] = osum / lsum;
}

// ---------------------------------------------------------------------------
extern "C" void kernel_launch(void* const* d_in, const int* in_sizes, int n_in,
                              void* d_out, int out_size, void* d_ws, size_t ws_size,
                              hipStream_t stream) {
  const float* bev     = (const float*)d_in[0];
  const float* queries = (const float*)d_in[1];
  const float* Wq      = (const float*)d_in[2];
  const float* bq      = (const float*)d_in[3];
  const float* Wk      = (const float*)d_in[4];
  const float* bk      = (const float*)d_in[5];
  const float* Wv      = (const float*)d_in[6];
  const float* bv      = (const float*)d_in[7];
  const float* Wo      = (const float*)d_in[8];
  const float* bo      = (const float*)d_in[9];
  float* out = (float*)d_out;

  // workspace layout (f32): q | k | v | o | Opart | mpart | lpart
  const size_t nq = (size_t)B_ * LQ_ * E_;  // 524288
  const size_t nk = (size_t)B_ * LK_ * E_;  // 5120000
  float* qws = (float*)d_ws;
  float* kws = qws + nq;
  float* vws = kws + nk;
  float* ows = vws + nk;
  float* opart = ows + nq;

  const size_t base_floats = nq * 2 + nk * 2;
  // choose split count that fits ws: S*(B*H*LQ)*(D+2) extra floats
  const size_t per_split = (size_t)B_ * H_ * LQ_ * (D_ + 2);
  int S = 0;  // 0 => direct path (no partials)
  for (int cand = 4; cand >= 1; cand >>= 1) {
    if ((base_floats + (size_t)cand * per_split) * sizeof(float) <= ws_size) {
      S = cand;
      break;
    }
  }

  const int MQ = B_ * LQ_;  // 2048
  const int MK = B_ * LK_;  // 20000
  const int NT = (LK_ + 63) / 64;  // 157

  proj_gemm<<<dim3(16, 2), 256, 0, stream>>>(queries, Wq, bq, qws, MQ);
  proj_gemm<<<dim3(157, 2), 256, 0, stream>>>(bev, Wk, bk, kws, MK);
  proj_gemm<<<dim3(157, 2), 256, 0, stream>>>(bev, Wv, bv, vws, MK);

  if (S == 0) {
    // direct (single-split, normalized in-kernel)
    flash_attn_f32<<<dim3(LQ_ / 32, H_, B_), 256, 0, stream>>>(
        qws, kws, vws, nullptr, nullptr, nullptr, ows, NT, 1);
  } else {
    float* mpart = opart + (size_t)S * B_ * H_ * LQ_ * D_;
    float* lpart = mpart + (size_t)S * B_ * H_ * LQ_;
    const int tps = (NT + S - 1) / S;
    flash_attn_f32<<<dim3(LQ_ / 32, H_, B_ * S), 256, 0, stream>>>(
        qws, kws, vws, opart, mpart, lpart, nullptr, tps, 0);
    attn_merge<<<dim3((B_ * LQ_ * E_ + 255) / 256), 256, 0, stream>>>(
        opart, mpart, lpart, ows, S);
  }

  proj_gemm<<<dim3(16, 2), 256, 0, stream>>>(ows, Wo, bo, out, MQ);
}

// Round 4
// 265.535 us; speedup vs baseline: 3.0894x; 2.5906x over previous
//
#include <hip/hip_runtime.h>
#include <hip/hip_bf16.h>

// Problem dims (fixed by reference)
#define B_  2
#define LQ_ 1024
#define LK_ 10000
#define E_  256
#define H_  8
#define D_  32

typedef __attribute__((ext_vector_type(8))) short bf16x8;
typedef __attribute__((ext_vector_type(4))) short bf16x4;
typedef __attribute__((ext_vector_type(4))) float f32x4;
typedef __attribute__((ext_vector_type(8))) unsigned short u16x8;

#define LOG2E 1.4426950408889634f

static __device__ __forceinline__ unsigned short f2bf(float f) {
  union { float f; unsigned int u; } a;
  a.f = f;
  unsigned int u = a.u;
  unsigned int r = (u + 0x7fffu + ((u >> 16) & 1u)) >> 16;  // RNE
  return (unsigned short)r;
}

// fast exp2 (v_exp_f32). NOTE: __exp2f collides with a glibc identifier.
#if __has_builtin(__builtin_amdgcn_exp2f)
static __device__ __forceinline__ float ex2(float x) {
  return __builtin_amdgcn_exp2f(x);
}
#else
static __device__ __forceinline__ float ex2(float x) { return exp2f(x); }
#endif

#if __has_builtin(__builtin_amdgcn_mfma_f32_16x16x16bf16_1k)
static __device__ __forceinline__ f32x4 mfma_pv(bf16x4 a, bf16x4 b, f32x4 c) {
  return __builtin_amdgcn_mfma_f32_16x16x16bf16_1k(a, b, c, 0, 0, 0);
}
#else
static __device__ __forceinline__ f32x4 mfma_pv(bf16x4 a, bf16x4 b, f32x4 c) {
  asm volatile("s_nop 1\n\tv_mfma_f32_16x16x16_bf16 %0, %1, %2, %0"
               : "+v"(c) : "v"(a), "v"(b));
  return c;
}
#endif

// ---------------------------------------------------------------------------
// proj_gemm_t: C[M,256] = A[M,256] @ W[256,256] + bias  (f32 math)
// BF16OUT: store bf16 (for K/V feeding the MFMA attention), else f32.
// ---------------------------------------------------------------------------
template <bool BF16OUT>
__global__ __launch_bounds__(256) void proj_gemm_t(const float* __restrict__ A,
                                                   const float* __restrict__ W,
                                                   const float* __restrict__ bias,
                                                   void* __restrict__ Cout, int M) {
  const int m0 = blockIdx.x * 128;
  const int n0 = blockIdx.y * 128;
  const int t  = threadIdx.x;
  const int tx = t & 15;
  const int ty = t >> 4;

  __shared__ __align__(16) float As[8][128];
  __shared__ __align__(16) float Ws[8][128];

  float acc[8][8];
#pragma unroll
  for (int i = 0; i < 8; ++i)
#pragma unroll
    for (int j = 0; j < 8; ++j) acc[i][j] = 0.f;

  const int arow  = t >> 1;
  const int ahalf = t & 1;
  const int wk    = t >> 5;
  const int wc    = t & 31;

  for (int k0 = 0; k0 < 256; k0 += 8) {
    float4 av = make_float4(0.f, 0.f, 0.f, 0.f);
    if (m0 + arow < M)
      av = *(const float4*)&A[(size_t)(m0 + arow) * 256 + k0 + ahalf * 4];
    const float4 wv = *(const float4*)&W[(size_t)(k0 + wk) * 256 + n0 + wc * 4];
    __syncthreads();
    As[ahalf * 4 + 0][arow] = av.x;
    As[ahalf * 4 + 1][arow] = av.y;
    As[ahalf * 4 + 2][arow] = av.z;
    As[ahalf * 4 + 3][arow] = av.w;
    *(float4*)&Ws[wk][wc * 4] = wv;
    __syncthreads();
#pragma unroll
    for (int kk = 0; kk < 8; ++kk) {
      float a[8], w[8];
      *(float4*)&a[0] = *(const float4*)&As[kk][ty * 8];
      *(float4*)&a[4] = *(const float4*)&As[kk][ty * 8 + 4];
      *(float4*)&w[0] = *(const float4*)&Ws[kk][tx * 8];
      *(float4*)&w[4] = *(const float4*)&Ws[kk][tx * 8 + 4];
#pragma unroll
      for (int i = 0; i < 8; ++i)
#pragma unroll
        for (int j = 0; j < 8; ++j) acc[i][j] = fmaf(a[i], w[j], acc[i][j]);
    }
  }

#pragma unroll
  for (int i = 0; i < 8; ++i) {
    const int row = m0 + ty * 8 + i;
    if (row < M) {
      const float* bptr = &bias[n0 + tx * 8];
      if (BF16OUT) {
        unsigned short* C = (unsigned short*)Cout;
        u16x8 o;
#pragma unroll
        for (int j = 0; j < 8; ++j) o[j] = f2bf(acc[i][j] + bptr[j]);
        *(u16x8*)&C[(size_t)row * 256 + n0 + tx * 8] = o;
      } else {
        float* C = (float*)Cout;
        float4 o0, o1;
        o0.x = acc[i][0] + bptr[0]; o0.y = acc[i][1] + bptr[1];
        o0.z = acc[i][2] + bptr[2]; o0.w = acc[i][3] + bptr[3];
        o1.x = acc[i][4] + bptr[4]; o1.y = acc[i][5] + bptr[5];
        o1.z = acc[i][6] + bptr[6]; o1.w = acc[i][7] + bptr[7];
        *(float4*)&C[(size_t)row * 256 + n0 + tx * 8]     = o0;
        *(float4*)&C[(size_t)row * 256 + n0 + tx * 8 + 4] = o1;
      }
    }
  }
}

// ---------------------------------------------------------------------------
// attn_mfma: 4 waves/block, 64 q-rows/block (16 per wave), 64-k tiles.
// S^T = K·Q^T via mfma_16x16x32 (lane holds q=lane&15, 16 k-vals in regs);
// softmax in-register (2 shfl_xor); P feeds mfma_16x16x16 B-frag directly;
// O^T accumulated per-lane with matching q ownership.
// q: f32 [B*LQ,256]; kbf/vbf: bf16 [B*LK,256] (as ushort).
// ---------------------------------------------------------------------------
__global__ __launch_bounds__(256) void attn_mfma(const float* __restrict__ q,
                                                 const unsigned short* __restrict__ kbf,
                                                 const unsigned short* __restrict__ vbf,
                                                 float* __restrict__ Opart,
                                                 float* __restrict__ mpart,
                                                 float* __restrict__ lpart,
                                                 float* __restrict__ o_direct,
                                                 int tiles_per_split, int nsplit) {
  const int qb   = blockIdx.x;      // 16 q-blocks of 64
  const int h    = blockIdx.y;      // 8 heads
  const int z    = blockIdx.z;      // s*B + b
  const int s_id = z / B_;
  const int b    = z % B_;
  const int t    = threadIdx.x;
  const int lane = t & 63;
  const int w    = t >> 6;          // wave 0..3
  const int lq   = lane & 15;       // q-col ownership
  const int grp  = lane >> 4;       // 0..3

  // LDS: K row-major [64][64 ushort] (128B rows, swizzled); V^T [32][64]
  __shared__ ushort Klds[64][64];
  __shared__ ushort Vtld[32][64];

  const int NT = (LK_ + 63) / 64;   // 157
  const int t0 = s_id * tiles_per_split;
  const int t1 = min(NT, t0 + tiles_per_split);

  // Q fragment (B-operand of QK mfma): row qb*64+w*16+lq, d = grp*8..+7,
  // pre-scaled by log2e so softmax uses exp2.
  const int qrow = qb * 64 + w * 16 + lq;
  bf16x8 qfrag;
  {
    const float* qp = &q[((size_t)(b * LQ_ + qrow)) * E_ + h * D_ + grp * 8];
    const float4 q0 = *(const float4*)qp;
    const float4 q1 = *(const float4*)(qp + 4);
    qfrag[0] = (short)f2bf(q0.x * LOG2E); qfrag[1] = (short)f2bf(q0.y * LOG2E);
    qfrag[2] = (short)f2bf(q0.z * LOG2E); qfrag[3] = (short)f2bf(q0.w * LOG2E);
    qfrag[4] = (short)f2bf(q1.x * LOG2E); qfrag[5] = (short)f2bf(q1.y * LOG2E);
    qfrag[6] = (short)f2bf(q1.z * LOG2E); qfrag[7] = (short)f2bf(q1.w * LOG2E);
  }

  // staging index maps
  const int krow_l = t >> 2;        // 0..63
  const int kchunk = t & 3;         // 16B chunk
  const int vkp    = t >> 3;        // 0..31 -> k rows 2vkp, 2vkp+1
  const int vd     = (t & 7) * 4;   // d quad

  float m_run = -1e30f;  // log2-domain running max
  float l_run = 0.f;
  f32x4 acc0 = {0.f, 0.f, 0.f, 0.f};  // O^T d = 0..15  (grp*4+reg)
  f32x4 acc1 = {0.f, 0.f, 0.f, 0.f};  // O^T d = 16..31

  const size_t kvrow0 = (size_t)b * LK_;

  for (int kt = t0; kt < t1; ++kt) {
    const int kv0 = kt * 64;
    const int rem = LK_ - kv0;  // valid k in this tile (>=1)

    // ---- issue global loads (regs only) ----
    uint4 kval = *(const uint4*)&kbf[(kvrow0 + kv0 + krow_l) * E_ + h * D_ + kchunk * 8];
    ushort4 v0 = {0, 0, 0, 0}, v1 = {0, 0, 0, 0};
    if (kv0 + 2 * vkp < LK_)
      v0 = *(const ushort4*)&vbf[(kvrow0 + kv0 + 2 * vkp) * E_ + h * D_ + vd];
    if (kv0 + 2 * vkp + 1 < LK_)
      v1 = *(const ushort4*)&vbf[(kvrow0 + kv0 + 2 * vkp + 1) * E_ + h * D_ + vd];

    __syncthreads();  // prior tile's LDS reads done

    // ---- LDS writes (swizzled) ----
    *(uint4*)((char*)&Klds[krow_l][0] + ((kchunk * 16) ^ ((krow_l & 7) << 4))) = kval;
#pragma unroll
    for (int i = 0; i < 4; ++i) {
      const int d = vd + i;
      *(ushort2*)((char*)&Vtld[d][0] + ((vkp * 4) ^ ((d & 7) << 4))) =
          make_ushort2(((const unsigned short*)&v0)[i], ((const unsigned short*)&v1)[i]);
    }
    __syncthreads();

    // ---- S^T = K · Q^T : 4 subtiles of 16 k ----
    f32x4 p[4];
#pragma unroll
    for (int s = 0; s < 4; ++s) {
      const int row = s * 16 + lq;
      const bf16x8 kf = *(const bf16x8*)((const char*)&Klds[row][0] +
                                         ((grp * 16) ^ ((row & 7) << 4)));
      const f32x4 zero = {0.f, 0.f, 0.f, 0.f};
      p[s] = __builtin_amdgcn_mfma_f32_16x16x32_bf16(kf, qfrag, zero, 0, 0, 0);
    }

    // ---- online softmax (log2 domain), lane-local + 2 shfl ----
    float pm = -1e30f;
    if (rem >= 64) {
#pragma unroll
      for (int s = 0; s < 4; ++s)
#pragma unroll
        for (int r = 0; r < 4; ++r) pm = fmaxf(pm, p[s][r]);
    } else {
#pragma unroll
      for (int s = 0; s < 4; ++s)
        if (s * 16 + grp * 4 < rem)
#pragma unroll
          for (int r = 0; r < 4; ++r) pm = fmaxf(pm, p[s][r]);
    }
    pm = fmaxf(pm, __shfl_xor(pm, 16));
    pm = fmaxf(pm, __shfl_xor(pm, 32));
    const float mnew = fmaxf(m_run, pm);
    const float fs   = ex2(m_run - mnew);

    float psum = 0.f;
    bf16x4 pb[4];
    if (rem >= 64) {
#pragma unroll
      for (int s = 0; s < 4; ++s)
#pragma unroll
        for (int r = 0; r < 4; ++r) {
          const float e = ex2(p[s][r] - mnew);
          psum += e;
          pb[s][r] = (short)f2bf(e);
        }
    } else {
#pragma unroll
      for (int s = 0; s < 4; ++s) {
        const bool vs = (s * 16 + grp * 4) < rem;
#pragma unroll
        for (int r = 0; r < 4; ++r) {
          const float e = vs ? ex2(p[s][r] - mnew) : 0.f;
          psum += e;
          pb[s][r] = (short)f2bf(e);
        }
      }
    }
    psum += __shfl_xor(psum, 16);
    psum += __shfl_xor(psum, 32);
    m_run = mnew;
    l_run = l_run * fs + psum;

    // ---- O^T accumulate: 8x mfma_16x16x16 ----
#pragma unroll
    for (int r = 0; r < 4; ++r) { acc0[r] *= fs; acc1[r] *= fs; }
#pragma unroll
    for (int s = 0; s < 4; ++s) {
      {
        const int row = lq;  // d 0..15
        const bf16x4 vf = *(const bf16x4*)((const char*)&Vtld[row][0] +
                                           ((s * 32 + grp * 8) ^ ((row & 7) << 4)));
        acc0 = mfma_pv(vf, pb[s], acc0);
      }
      {
        const int row = 16 + lq;  // d 16..31
        const bf16x4 vf = *(const bf16x4*)((const char*)&Vtld[row][0] +
                                           ((s * 32 + grp * 8) ^ ((row & 7) << 4)));
        acc1 = mfma_pv(vf, pb[s], acc1);
      }
    }
  }

  // ---- epilogue: lane owns q = lq, d = {grp*4+r, 16+grp*4+r} ----
  if (nsplit == 1) {
    const float inv = 1.f / l_run;
    float* op = &o_direct[((size_t)(b * LQ_ + qrow)) * E_ + h * D_];
#pragma unroll
    for (int r = 0; r < 4; ++r) {
      op[grp * 4 + r]      = acc0[r] * inv;
      op[16 + grp * 4 + r] = acc1[r] * inv;
    }
  } else {
    const size_t pbase =
        (size_t)s_id * (B_ * H_ * LQ_) + ((size_t)b * H_ + h) * LQ_ + qrow;
#pragma unroll
    for (int r = 0; r < 4; ++r) {
      Opart[pbase * D_ + grp * 4 + r]      = acc0[r];
      Opart[pbase * D_ + 16 + grp * 4 + r] = acc1[r];
    }
    if (grp == 0) {
      mpart[pbase] = m_run;
      lpart[pbase] = l_run;
    }
  }
}

// ---------------------------------------------------------------------------
// attn_merge: combine split partials -> normalized o [B*LQ, E]
// (mpart is in log2 domain -> use exp2)
// ---------------------------------------------------------------------------
__global__ __launch_bounds__(256) void attn_merge(const float* __restrict__ Opart,
                                                  const float* __restrict__ mpart,
                                                  const float* __restrict__ lpart,
                                                  float* __restrict__ o, int S) {
  const int idx = blockIdx.x * 256 + threadIdx.x;
  if (idx >= B_ * LQ_ * E_) return;
  const int e   = idx & (E_ - 1);
  const int row = idx >> 8;
  const int b   = row >> 10;
  const int qq  = row & (LQ_ - 1);
  const int h   = e >> 5;
  const int d   = e & (D_ - 1);
  const size_t base   = ((size_t)b * H_ + h) * LQ_ + qq;
  const size_t stride = (size_t)B_ * H_ * LQ_;

  float mmax = -1e30f;
  for (int s = 0; s < S; ++s) mmax = fmaxf(mmax, mpart[s * stride + base]);
  float lsum = 0.f, osum = 0.f;
  for (int s = 0; s < S; ++s) {
    const float wgt = ex2(mpart[s * stride + base] - mmax);
    lsum += wgt * lpart[s * stride + base];
    osum += wgt * Opart[(s * stride + base) * D_ + d];
  }
  o[idx] = osum / lsum;
}

// ---------------------------------------------------------------------------
extern "C" void kernel_launch(void* const* d_in, const int* in_sizes, int n_in,
                              void* d_out, int out_size, void* d_ws, size_t ws_size,
                              hipStream_t stream) {
  const float* bev     = (const float*)d_in[0];
  const float* queries = (const float*)d_in[1];
  const float* Wq      = (const float*)d_in[2];
  const float* bq      = (const float*)d_in[3];
  const float* Wk      = (const float*)d_in[4];
  const float* bk      = (const float*)d_in[5];
  const float* Wv      = (const float*)d_in[6];
  const float* bv      = (const float*)d_in[7];
  const float* Wo      = (const float*)d_in[8];
  const float* bo      = (const float*)d_in[9];
  float* out = (float*)d_out;

  // ws layout: q f32 | k bf16 | v bf16 | o f32 | Opart f32 | mpart | lpart
  const size_t nq = (size_t)B_ * LQ_ * E_;  // 524288
  const size_t nk = (size_t)B_ * LK_ * E_;  // 5120000
  float*          qws = (float*)d_ws;
  unsigned short* kbf = (unsigned short*)(qws + nq);
  unsigned short* vbf = kbf + nk;
  float*          ows = (float*)(vbf + nk);
  float*          opart = ows + nq;

  const size_t base_bytes = (nq * 2) * sizeof(float) + (nk * 2) * sizeof(unsigned short);
  const size_t per_split_bytes = (size_t)B_ * H_ * LQ_ * (D_ + 2) * sizeof(float);
  int S = 0;
  for (int cand = 8; cand >= 1; cand >>= 1) {
    if (base_bytes + (size_t)cand * per_split_bytes <= ws_size) { S = cand; break; }
  }

  const int MQ = B_ * LQ_;         // 2048
  const int MK = B_ * LK_;         // 20000
  const int NT = (LK_ + 63) / 64;  // 157

  proj_gemm_t<false><<<dim3(16, 2), 256, 0, stream>>>(queries, Wq, bq, qws, MQ);
  proj_gemm_t<true><<<dim3(157, 2), 256, 0, stream>>>(bev, Wk, bk, kbf, MK);
  proj_gemm_t<true><<<dim3(157, 2), 256, 0, stream>>>(bev, Wv, bv, vbf, MK);

  if (S <= 1) {
    attn_mfma<<<dim3(16, H_, B_), 256, 0, stream>>>(
        qws, kbf, vbf, nullptr, nullptr, nullptr, ows, NT, 1);
  } else {
    float* mpart = opart + (size_t)S * B_ * H_ * LQ_ * D_;
    float* lpart = mpart + (size_t)S * B_ * H_ * LQ_;
    const int tps = (NT + S - 1) / S;
    attn_mfma<<<dim3(16, H_, B_ * S), 256, 0, stream>>>(
        qws, kbf, vbf, opart, mpart, lpart, nullptr, tps, S);
    attn_merge<<<dim3((B_ * LQ_ * E_ + 255) / 256), 256, 0, stream>>>(
        opart, mpart, lpart, ows, S);
  }

  proj_gemm_t<false><<<dim3(16, 2), 256, 0, stream>>>(ows, Wo, bo, out, MQ);
}

// Round 5
// 218.214 us; speedup vs baseline: 3.7594x; 1.2169x over previous
//
#include <hip/hip_runtime.h>
#include <hip/hip_bf16.h>

// Problem dims (fixed by reference)
#define B_  2
#define LQ_ 1024
#define LK_ 10000
#define E_  256
#define H_  8
#define D_  32

typedef __attribute__((ext_vector_type(8))) short bf16x8;
typedef __attribute__((ext_vector_type(4))) short bf16x4;
typedef __attribute__((ext_vector_type(4))) float f32x4;

#define LOG2E 1.4426950408889634f

// float -> bf16 via native cast (compiler pairs into v_cvt_pk_bf16_f32)
static __device__ __forceinline__ short bfc(float x) {
  __bf16 b = (__bf16)x;
  return __builtin_bit_cast(short, b);
}
static __device__ __forceinline__ float bf2f(short s) {
  return (float)__builtin_bit_cast(__bf16, s);
}

// fast exp2 (v_exp_f32). NOTE: __exp2f collides with a glibc identifier.
#if __has_builtin(__builtin_amdgcn_exp2f)
static __device__ __forceinline__ float ex2(float x) {
  return __builtin_amdgcn_exp2f(x);
}
#else
static __device__ __forceinline__ float ex2(float x) { return exp2f(x); }
#endif

#if __has_builtin(__builtin_amdgcn_mfma_f32_16x16x16bf16_1k)
static __device__ __forceinline__ f32x4 mfma_pv(bf16x4 a, bf16x4 b, f32x4 c) {
  return __builtin_amdgcn_mfma_f32_16x16x16bf16_1k(a, b, c, 0, 0, 0);
}
#else
static __device__ __forceinline__ f32x4 mfma_pv(bf16x4 a, bf16x4 b, f32x4 c) {
  asm volatile("s_nop 1\n\tv_mfma_f32_16x16x16_bf16 %0, %1, %2, %0"
               : "+v"(c) : "v"(a), "v"(b));
  return c;
}
#endif

// ---------------------------------------------------------------------------
// proj_f32: C[M,256] = A[M,256] @ W[256,256] + bias (all f32). For Q/O proj.
// ---------------------------------------------------------------------------
__global__ __launch_bounds__(256) void proj_f32(const float* __restrict__ A,
                                                const float* __restrict__ W,
                                                const float* __restrict__ bias,
                                                float* __restrict__ C, int M) {
  const int m0 = blockIdx.x * 128;
  const int n0 = blockIdx.y * 128;
  const int t  = threadIdx.x;
  const int tx = t & 15;
  const int ty = t >> 4;

  __shared__ __align__(16) float As[8][128];
  __shared__ __align__(16) float Ws[8][128];

  float acc[8][8];
#pragma unroll
  for (int i = 0; i < 8; ++i)
#pragma unroll
    for (int j = 0; j < 8; ++j) acc[i][j] = 0.f;

  const int arow  = t >> 1;
  const int ahalf = t & 1;
  const int wk    = t >> 5;
  const int wc    = t & 31;

  for (int k0 = 0; k0 < 256; k0 += 8) {
    float4 av = make_float4(0.f, 0.f, 0.f, 0.f);
    if (m0 + arow < M)
      av = *(const float4*)&A[(size_t)(m0 + arow) * 256 + k0 + ahalf * 4];
    const float4 wv = *(const float4*)&W[(size_t)(k0 + wk) * 256 + n0 + wc * 4];
    __syncthreads();
    As[ahalf * 4 + 0][arow] = av.x;
    As[ahalf * 4 + 1][arow] = av.y;
    As[ahalf * 4 + 2][arow] = av.z;
    As[ahalf * 4 + 3][arow] = av.w;
    *(float4*)&Ws[wk][wc * 4] = wv;
    __syncthreads();
#pragma unroll
    for (int kk = 0; kk < 8; ++kk) {
      float a[8], w[8];
      *(float4*)&a[0] = *(const float4*)&As[kk][ty * 8];
      *(float4*)&a[4] = *(const float4*)&As[kk][ty * 8 + 4];
      *(float4*)&w[0] = *(const float4*)&Ws[kk][tx * 8];
      *(float4*)&w[4] = *(const float4*)&Ws[kk][tx * 8 + 4];
#pragma unroll
      for (int i = 0; i < 8; ++i)
#pragma unroll
        for (int j = 0; j < 8; ++j) acc[i][j] = fmaf(a[i], w[j], acc[i][j]);
    }
  }

#pragma unroll
  for (int i = 0; i < 8; ++i) {
    const int row = m0 + ty * 8 + i;
    if (row < M) {
      const float* bptr = &bias[n0 + tx * 8];
      float4 o0, o1;
      o0.x = acc[i][0] + bptr[0]; o0.y = acc[i][1] + bptr[1];
      o0.z = acc[i][2] + bptr[2]; o0.w = acc[i][3] + bptr[3];
      o1.x = acc[i][4] + bptr[4]; o1.y = acc[i][5] + bptr[5];
      o1.z = acc[i][6] + bptr[6]; o1.w = acc[i][7] + bptr[7];
      *(float4*)&C[(size_t)row * 256 + n0 + tx * 8]     = o0;
      *(float4*)&C[(size_t)row * 256 + n0 + tx * 8 + 4] = o1;
    }
  }
}

// ---------------------------------------------------------------------------
// wtrans: Wt_bf16[n][k] = bf16(W[k][n]). 16x16 LDS tile transpose.
// ---------------------------------------------------------------------------
__global__ __launch_bounds__(256) void wtrans(const float* __restrict__ W,
                                              unsigned short* __restrict__ Wt) {
  __shared__ float ts[16][17];
  const int tx = threadIdx.x & 15;
  const int ty = threadIdx.x >> 4;
  const int k0 = blockIdx.x * 16;
  const int n0 = blockIdx.y * 16;
  ts[ty][tx] = W[(size_t)(k0 + ty) * 256 + n0 + tx];  // coalesced along n
  __syncthreads();
  Wt[(size_t)(n0 + ty) * 256 + k0 + tx] = (unsigned short)bfc(ts[tx][ty]);
}

// ---------------------------------------------------------------------------
// proj_mfma<NSPLIT>: C_bf16[M,256] = A_f32[M,256] @ W + bias, via 16x16x32
// bf16 MFMA. W passed pre-transposed bf16 (Wt[n][k]). NSPLIT=2: A split into
// hi+lo bf16 planes (2 MFMA passes) for near-f32 A precision.
// Tile 128x128, BK=32, 4 waves (2x2 of 64x64).
// ---------------------------------------------------------------------------
template <int NSPLIT>
__global__ __launch_bounds__(256) void proj_mfma(const float* __restrict__ A,
                                                 const unsigned short* __restrict__ Wt,
                                                 const float* __restrict__ bias,
                                                 unsigned short* __restrict__ C,
                                                 int M) {
  const int n0   = blockIdx.x * 128;  // N fastest -> A-tile reuse hits L2/L3
  const int m0   = blockIdx.y * 128;
  const int t    = threadIdx.x;
  const int lane = t & 63;
  const int w    = t >> 6;
  const int wr   = w >> 1;        // wave row-half (0..1)
  const int wcn  = w & 1;         // wave col-half (0..1)
  const int lr   = lane & 15;     // fragment row/col
  const int lk   = lane >> 4;     // k-octet (0..3)

  // rows padded to 56 ushorts (112 B): 16B-aligned, 8 distinct bank offsets
  __shared__ ushort Alds[NSPLIT][128][56];
  __shared__ ushort Wlds[128][56];

  f32x4 acc[4][4];
#pragma unroll
  for (int s = 0; s < 4; ++s)
#pragma unroll
    for (int q = 0; q < 4; ++q) acc[s][q] = (f32x4){0.f, 0.f, 0.f, 0.f};

  const int am = t >> 3;          // +i*32, rows 0..127
  const int ak = (t & 7) * 4;     // k quad
  const int wn = t >> 2;          // +i*64, rows 0..127 of Wt tile
  const int wkc = (t & 3) * 8;    // k octet

  for (int kb = 0; kb < 256; kb += 32) {
    __syncthreads();  // previous step's LDS reads done
    // stage A (f32 -> bf16 hi/lo)
#pragma unroll
    for (int i = 0; i < 4; ++i) {
      const int m = am + i * 32;
      float4 v = make_float4(0.f, 0.f, 0.f, 0.f);
      if (m0 + m < M) v = *(const float4*)&A[(size_t)(m0 + m) * 256 + kb + ak];
      ushort4 hi, lo;
      hi.x = (unsigned short)bfc(v.x); hi.y = (unsigned short)bfc(v.y);
      hi.z = (unsigned short)bfc(v.z); hi.w = (unsigned short)bfc(v.w);
      *(ushort4*)&Alds[0][m][ak] = hi;
      if (NSPLIT == 2) {
        lo.x = (unsigned short)bfc(v.x - bf2f((short)hi.x));
        lo.y = (unsigned short)bfc(v.y - bf2f((short)hi.y));
        lo.z = (unsigned short)bfc(v.z - bf2f((short)hi.z));
        lo.w = (unsigned short)bfc(v.w - bf2f((short)hi.w));
        *(ushort4*)&Alds[1][m][ak] = lo;
      }
    }
    // stage W (already bf16, [n][k])
#pragma unroll
    for (int i = 0; i < 2; ++i) {
      const int n = wn + i * 64;
      const uint4 wv = *(const uint4*)&Wt[(size_t)(n0 + n) * 256 + kb + wkc];
      *(uint4*)&Wlds[n][wkc] = wv;
    }
    __syncthreads();

    bf16x8 bfr[4];
#pragma unroll
    for (int q = 0; q < 4; ++q)
      bfr[q] = *(const bf16x8*)&Wlds[wcn * 64 + q * 16 + lr][lk * 8];
#pragma unroll
    for (int s = 0; s < 4; ++s) {
      const bf16x8 ah = *(const bf16x8*)&Alds[0][wr * 64 + s * 16 + lr][lk * 8];
#pragma unroll
      for (int q = 0; q < 4; ++q)
        acc[s][q] = __builtin_amdgcn_mfma_f32_16x16x32_bf16(ah, bfr[q], acc[s][q], 0, 0, 0);
      if (NSPLIT == 2) {
        const bf16x8 al = *(const bf16x8*)&Alds[1][wr * 64 + s * 16 + lr][lk * 8];
#pragma unroll
        for (int q = 0; q < 4; ++q)
          acc[s][q] = __builtin_amdgcn_mfma_f32_16x16x32_bf16(al, bfr[q], acc[s][q], 0, 0, 0);
      }
    }
  }

  // epilogue: D row = wr*64+s*16+lk*4+r, col = wcn*64+q*16+lr
#pragma unroll
  for (int q = 0; q < 4; ++q) {
    const int n = n0 + wcn * 64 + q * 16 + lr;
    const float bv = bias[n];
#pragma unroll
    for (int s = 0; s < 4; ++s) {
#pragma unroll
      for (int r = 0; r < 4; ++r) {
        const int m = m0 + wr * 64 + s * 16 + lk * 4 + r;
        if (m < M) C[(size_t)m * 256 + n] = (unsigned short)bfc(acc[s][q][r] + bv);
      }
    }
  }
}

// ---------------------------------------------------------------------------
// attn_mfma: 4 waves/block, 64 q-rows/block (16 per wave), 64-k tiles.
// S^T = K·Q^T via mfma_16x16x32; softmax in-register (2 shfl_xor, defer-max);
// P feeds mfma_16x16x16 B-frag directly; O^T per-lane.
// ---------------------------------------------------------------------------
__global__ __launch_bounds__(256) void attn_mfma(const float* __restrict__ q,
                                                 const unsigned short* __restrict__ kbf,
                                                 const unsigned short* __restrict__ vbf,
                                                 float* __restrict__ Opart,
                                                 float* __restrict__ mpart,
                                                 float* __restrict__ lpart,
                                                 float* __restrict__ o_direct,
                                                 int tiles_per_split, int nsplit) {
  const int qb   = blockIdx.x;
  const int h    = blockIdx.y;
  const int z    = blockIdx.z;
  const int s_id = z / B_;
  const int b    = z % B_;
  const int t    = threadIdx.x;
  const int lane = t & 63;
  const int w    = t >> 6;
  const int lq   = lane & 15;
  const int grp  = lane >> 4;

  __shared__ ushort Klds[64][64];
  __shared__ ushort Vtld[32][64];

  const int NT = (LK_ + 63) / 64;
  const int t0 = s_id * tiles_per_split;
  const int t1 = min(NT, t0 + tiles_per_split);

  const int qrow = qb * 64 + w * 16 + lq;
  bf16x8 qfrag;
  {
    const float* qp = &q[((size_t)(b * LQ_ + qrow)) * E_ + h * D_ + grp * 8];
    const float4 q0 = *(const float4*)qp;
    const float4 q1 = *(const float4*)(qp + 4);
    qfrag[0] = bfc(q0.x * LOG2E); qfrag[1] = bfc(q0.y * LOG2E);
    qfrag[2] = bfc(q0.z * LOG2E); qfrag[3] = bfc(q0.w * LOG2E);
    qfrag[4] = bfc(q1.x * LOG2E); qfrag[5] = bfc(q1.y * LOG2E);
    qfrag[6] = bfc(q1.z * LOG2E); qfrag[7] = bfc(q1.w * LOG2E);
  }

  const int krow_l = t >> 2;
  const int kchunk = t & 3;
  const int vkp    = t >> 3;
  const int vd     = (t & 7) * 4;

  float m_run = -1e30f;  // log2-domain running max
  float l_run = 0.f;
  f32x4 acc0 = {0.f, 0.f, 0.f, 0.f};
  f32x4 acc1 = {0.f, 0.f, 0.f, 0.f};

  const size_t kvrow0 = (size_t)b * LK_;

  for (int kt = t0; kt < t1; ++kt) {
    const int kv0 = kt * 64;
    const int rem = LK_ - kv0;

    uint4 kval = *(const uint4*)&kbf[(kvrow0 + kv0 + krow_l) * E_ + h * D_ + kchunk * 8];
    ushort4 v0 = {0, 0, 0, 0}, v1 = {0, 0, 0, 0};
    if (kv0 + 2 * vkp < LK_)
      v0 = *(const ushort4*)&vbf[(kvrow0 + kv0 + 2 * vkp) * E_ + h * D_ + vd];
    if (kv0 + 2 * vkp + 1 < LK_)
      v1 = *(const ushort4*)&vbf[(kvrow0 + kv0 + 2 * vkp + 1) * E_ + h * D_ + vd];

    __syncthreads();

    *(uint4*)((char*)&Klds[krow_l][0] + ((kchunk * 16) ^ ((krow_l & 7) << 4))) = kval;
#pragma unroll
    for (int i = 0; i < 4; ++i) {
      const int d = vd + i;
      *(ushort2*)((char*)&Vtld[d][0] + ((vkp * 4) ^ ((d & 7) << 4))) =
          make_ushort2(((const unsigned short*)&v0)[i], ((const unsigned short*)&v1)[i]);
    }
    __syncthreads();

    // S^T = K · Q^T
    f32x4 p[4];
#pragma unroll
    for (int s = 0; s < 4; ++s) {
      const int row = s * 16 + lq;
      const bf16x8 kf = *(const bf16x8*)((const char*)&Klds[row][0] +
                                         ((grp * 16) ^ ((row & 7) << 4)));
      const f32x4 zero = {0.f, 0.f, 0.f, 0.f};
      p[s] = __builtin_amdgcn_mfma_f32_16x16x32_bf16(kf, qfrag, zero, 0, 0, 0);
    }

    // online softmax (log2 domain), defer-max (THR=8 -> p <= 2^8)
    float pm = -1e30f;
    if (rem >= 64) {
#pragma unroll
      for (int s = 0; s < 4; ++s)
#pragma unroll
        for (int r = 0; r < 4; ++r) pm = fmaxf(pm, p[s][r]);
    } else {
#pragma unroll
      for (int s = 0; s < 4; ++s)
        if (s * 16 + grp * 4 < rem)
#pragma unroll
          for (int r = 0; r < 4; ++r) pm = fmaxf(pm, p[s][r]);
    }
    pm = fmaxf(pm, __shfl_xor(pm, 16));
    pm = fmaxf(pm, __shfl_xor(pm, 32));

    if (!__all(pm - m_run <= 8.0f)) {
      const float mnew = fmaxf(m_run, pm);
      const float fs   = ex2(m_run - mnew);
      m_run = mnew;
      l_run *= fs;
#pragma unroll
      for (int r = 0; r < 4; ++r) { acc0[r] *= fs; acc1[r] *= fs; }
    }

    float psum = 0.f;
    bf16x4 pb[4];
    if (rem >= 64) {
#pragma unroll
      for (int s = 0; s < 4; ++s)
#pragma unroll
        for (int r = 0; r < 4; ++r) {
          const float e = ex2(p[s][r] - m_run);
          psum += e;
          pb[s][r] = bfc(e);
        }
    } else {
#pragma unroll
      for (int s = 0; s < 4; ++s) {
        const bool vs = (s * 16 + grp * 4) < rem;
#pragma unroll
        for (int r = 0; r < 4; ++r) {
          const float e = vs ? ex2(p[s][r] - m_run) : 0.f;
          psum += e;
          pb[s][r] = bfc(e);
        }
      }
    }
    psum += __shfl_xor(psum, 16);
    psum += __shfl_xor(psum, 32);
    l_run += psum;

    // O^T accumulate
#pragma unroll
    for (int s = 0; s < 4; ++s) {
      {
        const int row = lq;
        const bf16x4 vf = *(const bf16x4*)((const char*)&Vtld[row][0] +
                                           ((s * 32 + grp * 8) ^ ((row & 7) << 4)));
        acc0 = mfma_pv(vf, pb[s], acc0);
      }
      {
        const int row = 16 + lq;
        const bf16x4 vf = *(const bf16x4*)((const char*)&Vtld[row][0] +
                                           ((s * 32 + grp * 8) ^ ((row & 7) << 4)));
        acc1 = mfma_pv(vf, pb[s], acc1);
      }
    }
  }

  if (nsplit == 1) {
    const float inv = 1.f / l_run;
    float* op = &o_direct[((size_t)(b * LQ_ + qrow)) * E_ + h * D_];
#pragma unroll
    for (int r = 0; r < 4; ++r) {
      op[grp * 4 + r]      = acc0[r] * inv;
      op[16 + grp * 4 + r] = acc1[r] * inv;
    }
  } else {
    const size_t pbase =
        (size_t)s_id * (B_ * H_ * LQ_) + ((size_t)b * H_ + h) * LQ_ + qrow;
#pragma unroll
    for (int r = 0; r < 4; ++r) {
      Opart[pbase * D_ + grp * 4 + r]      = acc0[r];
      Opart[pbase * D_ + 16 + grp * 4 + r] = acc1[r];
    }
    if (grp == 0) {
      mpart[pbase] = m_run;
      lpart[pbase] = l_run;
    }
  }
}

// ---------------------------------------------------------------------------
// attn_merge: combine split partials -> normalized o [B*LQ, E] (log2-domain m)
// ---------------------------------------------------------------------------
__global__ __launch_bounds__(256) void attn_merge(const float* __restrict__ Opart,
                                                  const float* __restrict__ mpart,
                                                  const float* __restrict__ lpart,
                                                  float* __restrict__ o, int S) {
  const int idx = blockIdx.x * 256 + threadIdx.x;
  if (idx >= B_ * LQ_ * E_) return;
  const int e   = idx & (E_ - 1);
  const int row = idx >> 8;
  const int b   = row >> 10;
  const int qq  = row & (LQ_ - 1);
  const int h   = e >> 5;
  const int d   = e & (D_ - 1);
  const size_t base   = ((size_t)b * H_ + h) * LQ_ + qq;
  const size_t stride = (size_t)B_ * H_ * LQ_;

  float mmax = -1e30f;
  for (int s = 0; s < S; ++s) mmax = fmaxf(mmax, mpart[s * stride + base]);
  float lsum = 0.f, osum = 0.f;
  for (int s = 0; s < S; ++s) {
    const float wgt = ex2(mpart[s * stride + base] - mmax);
    lsum += wgt * lpart[s * stride + base];
    osum += wgt * Opart[(s * stride + base) * D_ + d];
  }
  o[idx] = osum / lsum;
}

// ---------------------------------------------------------------------------
extern "C" void kernel_launch(void* const* d_in, const int* in_sizes, int n_in,
                              void* d_out, int out_size, void* d_ws, size_t ws_size,
                              hipStream_t stream) {
  const float* bev     = (const float*)d_in[0];
  const float* queries = (const float*)d_in[1];
  const float* Wq      = (const float*)d_in[2];
  const float* bq      = (const float*)d_in[3];
  const float* Wk      = (const float*)d_in[4];
  const float* bk      = (const float*)d_in[5];
  const float* Wv      = (const float*)d_in[6];
  const float* bv      = (const float*)d_in[7];
  const float* Wo      = (const float*)d_in[8];
  const float* bo      = (const float*)d_in[9];
  float* out = (float*)d_out;

  // ws: q f32 | k bf16 | v bf16 | o f32 | Wtk bf16 | Wtv bf16 | Opart | m | l
  const size_t nq = (size_t)B_ * LQ_ * E_;  // 524288
  const size_t nk = (size_t)B_ * LK_ * E_;  // 5120000
  const size_t nw = (size_t)E_ * E_;        // 65536
  float*          qws = (float*)d_ws;
  unsigned short* kbf = (unsigned short*)(qws + nq);
  unsigned short* vbf = kbf + nk;
  float*          ows = (float*)(vbf + nk);
  unsigned short* Wtk = (unsigned short*)(ows + nq);
  unsigned short* Wtv = Wtk + nw;
  float*          opart = (float*)(Wtv + nw);

  const size_t base_bytes = (nq * 2) * sizeof(float) +
                            (nk * 2 + nw * 2) * sizeof(unsigned short);
  const size_t per_split_bytes = (size_t)B_ * H_ * LQ_ * (D_ + 2) * sizeof(float);
  int S = 0;
  for (int cand = 8; cand >= 1; cand >>= 1) {
    if (base_bytes + (size_t)cand * per_split_bytes <= ws_size) { S = cand; break; }
  }

  const int MQ = B_ * LQ_;         // 2048
  const int MK = B_ * LK_;         // 20000
  const int NT = (LK_ + 63) / 64;  // 157

  wtrans<<<dim3(16, 16), 256, 0, stream>>>(Wk, Wtk);
  wtrans<<<dim3(16, 16), 256, 0, stream>>>(Wv, Wtv);

  proj_f32<<<dim3(16, 2), 256, 0, stream>>>(queries, Wq, bq, qws, MQ);
  proj_mfma<2><<<dim3(2, 157), 256, 0, stream>>>(bev, Wtk, bk, kbf, MK);
  proj_mfma<1><<<dim3(2, 157), 256, 0, stream>>>(bev, Wtv, bv, vbf, MK);

  if (S <= 1) {
    attn_mfma<<<dim3(16, H_, B_), 256, 0, stream>>>(
        qws, kbf, vbf, nullptr, nullptr, nullptr, ows, NT, 1);
  } else {
    float* mpart = opart + (size_t)S * B_ * H_ * LQ_ * D_;
    float* lpart = mpart + (size_t)S * B_ * H_ * LQ_;
    const int tps = (NT + S - 1) / S;
    attn_mfma<<<dim3(16, H_, B_ * S), 256, 0, stream>>>(
        qws, kbf, vbf, opart, mpart, lpart, nullptr, tps, S);
    attn_merge<<<dim3((B_ * LQ_ * E_ + 255) / 256), 256, 0, stream>>>(
        opart, mpart, lpart, ows, S);
  }

  proj_f32<<<dim3(16, 2), 256, 0, stream>>>(ows, Wo, bo, out, MQ);
}

// Round 7
// 176.656 us; speedup vs baseline: 4.6438x; 1.2353x over previous
//
#include <hip/hip_runtime.h>
#include <hip/hip_bf16.h>

// Problem dims (fixed by reference)
#define B_  2
#define LQ_ 1024
#define LK_ 10000
#define E_  256
#define H_  8
#define D_  32

typedef __attribute__((ext_vector_type(8))) short bf16x8;
typedef __attribute__((ext_vector_type(4))) short bf16x4;
typedef __attribute__((ext_vector_type(4))) float f32x4;

#define LOG2E 1.4426950408889634f

// float -> bf16 via native cast (compiler pairs into v_cvt_pk_bf16_f32)
static __device__ __forceinline__ short bfc(float x) {
  __bf16 b = (__bf16)x;
  return __builtin_bit_cast(short, b);
}
static __device__ __forceinline__ float bf2f(short s) {
  return (float)__builtin_bit_cast(__bf16, s);
}

// fast exp2 (v_exp_f32). NOTE: __exp2f collides with a glibc identifier.
#if __has_builtin(__builtin_amdgcn_exp2f)
static __device__ __forceinline__ float ex2(float x) {
  return __builtin_amdgcn_exp2f(x);
}
#else
static __device__ __forceinline__ float ex2(float x) { return exp2f(x); }
#endif

#if __has_builtin(__builtin_amdgcn_mfma_f32_16x16x16bf16_1k)
static __device__ __forceinline__ f32x4 mfma_pv(bf16x4 a, bf16x4 b, f32x4 c) {
  return __builtin_amdgcn_mfma_f32_16x16x16bf16_1k(a, b, c, 0, 0, 0);
}
#else
static __device__ __forceinline__ f32x4 mfma_pv(bf16x4 a, bf16x4 b, f32x4 c) {
  asm volatile("s_nop 1\n\tv_mfma_f32_16x16x16_bf16 %0, %1, %2, %0"
               : "+v"(c) : "v"(a), "v"(b));
  return c;
}
#endif

// m204 bijective XCD-chunked swizzle: blocks with the same (flat % 8) land on
// the same XCD (round-robin dispatch) and get CONSECUTIVE logical ids.
static __device__ __forceinline__ int xcd_swizzle(int flat, int nwg) {
  const int xcd = flat & 7, rest = flat >> 3;
  const int q = nwg >> 3, r = nwg & 7;
  return (xcd < r ? xcd * (q + 1) : r * (q + 1) + (xcd - r) * q) + rest;
}

// ---------------------------------------------------------------------------
// wtrans4: Wt_bf16[n][k] = bf16(W[k][n]) for 4 weights in one launch.
// ---------------------------------------------------------------------------
__global__ __launch_bounds__(256) void wtrans4(
    const float* __restrict__ W0, const float* __restrict__ W1,
    const float* __restrict__ W2, const float* __restrict__ W3,
    unsigned short* __restrict__ T0, unsigned short* __restrict__ T1,
    unsigned short* __restrict__ T2, unsigned short* __restrict__ T3) {
  const float* W;
  unsigned short* T;
  switch (blockIdx.z) {
    case 0:  W = W0; T = T0; break;
    case 1:  W = W1; T = T1; break;
    case 2:  W = W2; T = T2; break;
    default: W = W3; T = T3; break;
  }
  __shared__ float ts[16][17];
  const int tx = threadIdx.x & 15;
  const int ty = threadIdx.x >> 4;
  const int k0 = blockIdx.x * 16;
  const int n0 = blockIdx.y * 16;
  ts[ty][tx] = W[(size_t)(k0 + ty) * 256 + n0 + tx];  // coalesced along n
  __syncthreads();
  T[(size_t)(n0 + ty) * 256 + k0 + tx] = (unsigned short)bfc(ts[tx][ty]);
}

// ---------------------------------------------------------------------------
// proj_mfma<NSPLIT,F32OUT>: C[M,256] = A_f32[M,256] @ W + bias via 16x16x32
// bf16 MFMA. W pre-transposed bf16 (Wt[n][k]). NSPLIT=2: A split hi+lo bf16
// (2 MFMA passes) -> near-f32 A precision (error ~= W bf16 rounding only).
// Tile 128x128, BK=32, 4 waves (2x2 of 64x64).
// ---------------------------------------------------------------------------
template <int NSPLIT, bool F32OUT>
__global__ __launch_bounds__(256) void proj_mfma(const float* __restrict__ A,
                                                 const unsigned short* __restrict__ Wt,
                                                 const float* __restrict__ bias,
                                                 void* __restrict__ Cv, int M) {
  // XCD swizzle: same-m0 blocks (sharing the A tile) land on one XCD
  const int nwg  = gridDim.x * gridDim.y;
  const int wg   = xcd_swizzle(blockIdx.x + gridDim.x * blockIdx.y, nwg);
  const int n0   = (wg % gridDim.x) * 128;
  const int m0   = (wg / gridDim.x) * 128;
  const int t    = threadIdx.x;
  const int lane = t & 63;
  const int w    = t >> 6;
  const int wr   = w >> 1;        // wave row-half (0..1)
  const int wcn  = w & 1;         // wave col-half (0..1)
  const int lr   = lane & 15;     // fragment row/col
  const int lk   = lane >> 4;     // k-octet (0..3)

  // rows padded to 56 ushorts (112 B): 16B-aligned, 8 distinct bank offsets
  __shared__ ushort Alds[NSPLIT][128][56];
  __shared__ ushort Wlds[128][56];

  f32x4 acc[4][4];
#pragma unroll
  for (int s = 0; s < 4; ++s)
#pragma unroll
    for (int q = 0; q < 4; ++q) acc[s][q] = (f32x4){0.f, 0.f, 0.f, 0.f};

  const int am = t >> 3;          // +i*32, rows 0..127
  const int ak = (t & 7) * 4;     // k quad
  const int wn = t >> 2;          // +i*64, rows 0..127 of Wt tile
  const int wkc = (t & 3) * 8;    // k octet

  for (int kb = 0; kb < 256; kb += 32) {
    __syncthreads();  // previous step's LDS reads done
    // stage A (f32 -> bf16 hi/lo)
#pragma unroll
    for (int i = 0; i < 4; ++i) {
      const int m = am + i * 32;
      float4 v = make_float4(0.f, 0.f, 0.f, 0.f);
      if (m0 + m < M) v = *(const float4*)&A[(size_t)(m0 + m) * 256 + kb + ak];
      ushort4 hi, lo;
      hi.x = (unsigned short)bfc(v.x); hi.y = (unsigned short)bfc(v.y);
      hi.z = (unsigned short)bfc(v.z); hi.w = (unsigned short)bfc(v.w);
      *(ushort4*)&Alds[0][m][ak] = hi;
      if (NSPLIT == 2) {
        lo.x = (unsigned short)bfc(v.x - bf2f((short)hi.x));
        lo.y = (unsigned short)bfc(v.y - bf2f((short)hi.y));
        lo.z = (unsigned short)bfc(v.z - bf2f((short)hi.z));
        lo.w = (unsigned short)bfc(v.w - bf2f((short)hi.w));
        *(ushort4*)&Alds[1][m][ak] = lo;
      }
    }
    // stage W (already bf16, [n][k])
#pragma unroll
    for (int i = 0; i < 2; ++i) {
      const int n = wn + i * 64;
      const uint4 wv = *(const uint4*)&Wt[(size_t)(n0 + n) * 256 + kb + wkc];
      *(uint4*)&Wlds[n][wkc] = wv;
    }
    __syncthreads();

    bf16x8 bfr[4];
#pragma unroll
    for (int q = 0; q < 4; ++q)
      bfr[q] = *(const bf16x8*)&Wlds[wcn * 64 + q * 16 + lr][lk * 8];
#pragma unroll
    for (int s = 0; s < 4; ++s) {
      const bf16x8 ah = *(const bf16x8*)&Alds[0][wr * 64 + s * 16 + lr][lk * 8];
#pragma unroll
      for (int q = 0; q < 4; ++q)
        acc[s][q] = __builtin_amdgcn_mfma_f32_16x16x32_bf16(ah, bfr[q], acc[s][q], 0, 0, 0);
      if (NSPLIT == 2) {
        const bf16x8 al = *(const bf16x8*)&Alds[1][wr * 64 + s * 16 + lr][lk * 8];
#pragma unroll
        for (int q = 0; q < 4; ++q)
          acc[s][q] = __builtin_amdgcn_mfma_f32_16x16x32_bf16(al, bfr[q], acc[s][q], 0, 0, 0);
      }
    }
  }

  // epilogue: D row = wr*64+s*16+lk*4+r, col = wcn*64+q*16+lr
#pragma unroll
  for (int q = 0; q < 4; ++q) {
    const int n = n0 + wcn * 64 + q * 16 + lr;
    const float bv = bias[n];
#pragma unroll
    for (int s = 0; s < 4; ++s) {
#pragma unroll
      for (int r = 0; r < 4; ++r) {
        const int m = m0 + wr * 64 + s * 16 + lk * 4 + r;
        if (m < M) {
          if (F32OUT) {
            ((float*)Cv)[(size_t)m * 256 + n] = acc[s][q][r] + bv;
          } else {
            ((unsigned short*)Cv)[(size_t)m * 256 + n] =
                (unsigned short)bfc(acc[s][q][r] + bv);
          }
        }
      }
    }
  }
}

// ---------------------------------------------------------------------------
// attn_mfma: 4 waves/block, 64 q-rows/block (16/wave), 64-k tiles.
// S^T = K·Q^T via mfma_16x16x32; softmax in-register (2 shfl_xor, defer-max);
// P feeds mfma_16x16x16 B-frag directly; O^T per-lane.
// Pipeline: tile t+1's global loads issue BEFORE tile t's compute (T14).
// Tail rows CLAMPED to LK_-1: in-bounds + deterministic (an OOB read would
// see poison/stale d_ws bytes -> possible bf16-NaN, and NaN*0=NaN leaks
// through the P=0 masking). Clamped dup rows are masked exactly by p=0.
// XCD swizzle: 16 qb-blocks of one (h,z) share an XCD -> K/V L2-resident.
// ---------------------------------------------------------------------------
__global__ __launch_bounds__(256) void attn_mfma(const float* __restrict__ q,
                                                 const unsigned short* __restrict__ kbf,
                                                 const unsigned short* __restrict__ vbf,
                                                 float* __restrict__ Opart,
                                                 float* __restrict__ mpart,
                                                 float* __restrict__ lpart,
                                                 float* __restrict__ o_direct,
                                                 int tiles_per_split, int nsplit) {
  const int nwg = 128 * gridDim.z;
  const int l   = xcd_swizzle(blockIdx.x + 16 * (blockIdx.y + 8 * blockIdx.z), nwg);
  const int qb   = l & 15;
  const int h    = (l >> 4) & 7;
  const int z    = l >> 7;
  const int s_id = z / B_;
  const int b    = z % B_;
  const int t    = threadIdx.x;
  const int lane = t & 63;
  const int w    = t >> 6;
  const int lq   = lane & 15;
  const int grp  = lane >> 4;

  __shared__ ushort Klds[64][64];
  __shared__ ushort Vtld[32][64];

  const int NT = (LK_ + 63) / 64;
  const int t0 = s_id * tiles_per_split;
  const int t1 = min(NT, t0 + tiles_per_split);

  const int qrow = qb * 64 + w * 16 + lq;
  bf16x8 qfrag;
  {
    const float* qp = &q[((size_t)(b * LQ_ + qrow)) * E_ + h * D_ + grp * 8];
    const float4 q0 = *(const float4*)qp;
    const float4 q1 = *(const float4*)(qp + 4);
    qfrag[0] = bfc(q0.x * LOG2E); qfrag[1] = bfc(q0.y * LOG2E);
    qfrag[2] = bfc(q0.z * LOG2E); qfrag[3] = bfc(q0.w * LOG2E);
    qfrag[4] = bfc(q1.x * LOG2E); qfrag[5] = bfc(q1.y * LOG2E);
    qfrag[6] = bfc(q1.z * LOG2E); qfrag[7] = bfc(q1.w * LOG2E);
  }

  const int krow_l = t >> 2;
  const int kchunk = t & 3;
  const int vkp    = t >> 3;
  const int vd     = (t & 7) * 4;

  float m_run = -1e30f;  // log2-domain running max
  float l_run = 0.f;
  f32x4 acc0 = {0.f, 0.f, 0.f, 0.f};
  f32x4 acc1 = {0.f, 0.f, 0.f, 0.f};

  const size_t kvrow0 = (size_t)b * LK_;

  // prologue loads for tile t0 (always fully in-bounds: t0*64+63 < LK_)
  uint4 kval = *(const uint4*)&kbf[(kvrow0 + t0 * 64 + krow_l) * E_ + h * D_ + kchunk * 8];
  ushort4 v0 = *(const ushort4*)&vbf[(kvrow0 + t0 * 64 + 2 * vkp) * E_ + h * D_ + vd];
  ushort4 v1 = *(const ushort4*)&vbf[(kvrow0 + t0 * 64 + 2 * vkp + 1) * E_ + h * D_ + vd];

  for (int kt = t0; kt < t1; ++kt) {
    const int rem = LK_ - kt * 64;  // valid k this tile (rem%16==0 -> group masks exact)

    __syncthreads();  // prior tile's LDS reads done
    *(uint4*)((char*)&Klds[krow_l][0] + ((kchunk * 16) ^ ((krow_l & 7) << 4))) = kval;
#pragma unroll
    for (int i = 0; i < 4; ++i) {
      const int d = vd + i;
      *(ushort2*)((char*)&Vtld[d][0] + ((vkp * 4) ^ ((d & 7) << 4))) =
          make_ushort2(((const unsigned short*)&v0)[i], ((const unsigned short*)&v1)[i]);
    }
    __syncthreads();

    // prefetch next tile (latency hides under compute below); rows clamped
    if (kt + 1 < t1) {
      const int kn = (kt + 1) * 64;
      const int krow  = min(kn + krow_l, LK_ - 1);
      const int vrow0 = min(kn + 2 * vkp, LK_ - 1);
      const int vrow1 = min(kn + 2 * vkp + 1, LK_ - 1);
      kval = *(const uint4*)&kbf[(kvrow0 + krow) * E_ + h * D_ + kchunk * 8];
      v0 = *(const ushort4*)&vbf[(kvrow0 + vrow0) * E_ + h * D_ + vd];
      v1 = *(const ushort4*)&vbf[(kvrow0 + vrow1) * E_ + h * D_ + vd];
    }

    // S^T = K · Q^T
    f32x4 p[4];
    __builtin_amdgcn_s_setprio(1);
#pragma unroll
    for (int s = 0; s < 4; ++s) {
      const int row = s * 16 + lq;
      const bf16x8 kf = *(const bf16x8*)((const char*)&Klds[row][0] +
                                         ((grp * 16) ^ ((row & 7) << 4)));
      const f32x4 zero = {0.f, 0.f, 0.f, 0.f};
      p[s] = __builtin_amdgcn_mfma_f32_16x16x32_bf16(kf, qfrag, zero, 0, 0, 0);
    }
    __builtin_amdgcn_s_setprio(0);

    // online softmax (log2 domain), defer-max (THR=8 -> p <= 2^8)
    float pm = -1e30f;
    if (rem >= 64) {
#pragma unroll
      for (int s = 0; s < 4; ++s)
#pragma unroll
        for (int r = 0; r < 4; ++r) pm = fmaxf(pm, p[s][r]);
    } else {
#pragma unroll
      for (int s = 0; s < 4; ++s)
        if (s * 16 + grp * 4 < rem)
#pragma unroll
          for (int r = 0; r < 4; ++r) pm = fmaxf(pm, p[s][r]);
    }
    pm = fmaxf(pm, __shfl_xor(pm, 16));
    pm = fmaxf(pm, __shfl_xor(pm, 32));

    if (!__all(pm - m_run <= 8.0f)) {
      const float mnew = fmaxf(m_run, pm);
      const float fs   = ex2(m_run - mnew);
      m_run = mnew;
      l_run *= fs;
#pragma unroll
      for (int r = 0; r < 4; ++r) { acc0[r] *= fs; acc1[r] *= fs; }
    }

    float psum = 0.f;
    bf16x4 pb[4];
    if (rem >= 64) {
#pragma unroll
      for (int s = 0; s < 4; ++s)
#pragma unroll
        for (int r = 0; r < 4; ++r) {
          const float e = ex2(p[s][r] - m_run);
          psum += e;
          pb[s][r] = bfc(e);
        }
    } else {
#pragma unroll
      for (int s = 0; s < 4; ++s) {
        const bool vs = (s * 16 + grp * 4) < rem;
#pragma unroll
        for (int r = 0; r < 4; ++r) {
          const float e = vs ? ex2(p[s][r] - m_run) : 0.f;
          psum += e;
          pb[s][r] = bfc(e);
        }
      }
    }
    psum += __shfl_xor(psum, 16);
    psum += __shfl_xor(psum, 32);
    l_run += psum;

    // O^T accumulate
    __builtin_amdgcn_s_setprio(1);
#pragma unroll
    for (int s = 0; s < 4; ++s) {
      {
        const int row = lq;
        const bf16x4 vf = *(const bf16x4*)((const char*)&Vtld[row][0] +
                                           ((s * 32 + grp * 8) ^ ((row & 7) << 4)));
        acc0 = mfma_pv(vf, pb[s], acc0);
      }
      {
        const int row = 16 + lq;
        const bf16x4 vf = *(const bf16x4*)((const char*)&Vtld[row][0] +
                                           ((s * 32 + grp * 8) ^ ((row & 7) << 4)));
        acc1 = mfma_pv(vf, pb[s], acc1);
      }
    }
    __builtin_amdgcn_s_setprio(0);
  }

  if (nsplit == 1) {
    const float inv = 1.f / l_run;
    float* op = &o_direct[((size_t)(b * LQ_ + qrow)) * E_ + h * D_];
#pragma unroll
    for (int r = 0; r < 4; ++r) {
      op[grp * 4 + r]      = acc0[r] * inv;
      op[16 + grp * 4 + r] = acc1[r] * inv;
    }
  } else {
    const size_t pbase =
        (size_t)s_id * (B_ * H_ * LQ_) + ((size_t)b * H_ + h) * LQ_ + qrow;
#pragma unroll
    for (int r = 0; r < 4; ++r) {
      Opart[pbase * D_ + grp * 4 + r]      = acc0[r];
      Opart[pbase * D_ + 16 + grp * 4 + r] = acc1[r];
    }
    if (grp == 0) {
      mpart[pbase] = m_run;
      lpart[pbase] = l_run;
    }
  }
}

// ---------------------------------------------------------------------------
// attn_merge: combine split partials -> normalized o [B*LQ, E] (log2-domain m)
// ---------------------------------------------------------------------------
__global__ __launch_bounds__(256) void attn_merge(const float* __restrict__ Opart,
                                                  const float* __restrict__ mpart,
                                                  const float* __restrict__ lpart,
                                                  float* __restrict__ o, int S) {
  const int idx = blockIdx.x * 256 + threadIdx.x;
  if (idx >= B_ * LQ_ * E_) return;
  const int e   = idx & (E_ - 1);
  const int row = idx >> 8;
  const int b   = row >> 10;
  const int qq  = row & (LQ_ - 1);
  const int h   = e >> 5;
  const int d   = e & (D_ - 1);
  const size_t base   = ((size_t)b * H_ + h) * LQ_ + qq;
  const size_t stride = (size_t)B_ * H_ * LQ_;

  float mmax = -1e30f;
  for (int s = 0; s < S; ++s) mmax = fmaxf(mmax, mpart[s * stride + base]);
  float lsum = 0.f, osum = 0.f;
  for (int s = 0; s < S; ++s) {
    const float wgt = ex2(mpart[s * stride + base] - mmax);
    lsum += wgt * lpart[s * stride + base];
    osum += wgt * Opart[(s * stride + base) * D_ + d];
  }
  o[idx] = osum / lsum;
}

// ---------------------------------------------------------------------------
extern "C" void kernel_launch(void* const* d_in, const int* in_sizes, int n_in,
                              void* d_out, int out_size, void* d_ws, size_t ws_size,
                              hipStream_t stream) {
  const float* bev     = (const float*)d_in[0];
  const float* queries = (const float*)d_in[1];
  const float* Wq      = (const float*)d_in[2];
  const float* bq      = (const float*)d_in[3];
  const float* Wk      = (const float*)d_in[4];
  const float* bk      = (const float*)d_in[5];
  const float* Wv      = (const float*)d_in[6];
  const float* bv      = (const float*)d_in[7];
  const float* Wo      = (const float*)d_in[8];
  const float* bo      = (const float*)d_in[9];
  float* out = (float*)d_out;

  // ws: q f32 | k bf16 | v bf16 | o f32 | Wtq|Wtk|Wtv|Wto bf16 | Opart | m | l
  const size_t nq = (size_t)B_ * LQ_ * E_;  // 524288
  const size_t nk = (size_t)B_ * LK_ * E_;  // 5120000
  const size_t nw = (size_t)E_ * E_;        // 65536
  float*          qws = (float*)d_ws;
  unsigned short* kbf = (unsigned short*)(qws + nq);
  unsigned short* vbf = kbf + nk;
  float*          ows = (float*)(vbf + nk);
  unsigned short* Wtq = (unsigned short*)(ows + nq);
  unsigned short* Wtk = Wtq + nw;
  unsigned short* Wtv = Wtk + nw;
  unsigned short* Wto = Wtv + nw;
  float*          opart = (float*)(Wto + nw);

  const size_t base_bytes = (nq * 2) * sizeof(float) +
                            (nk * 2 + nw * 4) * sizeof(unsigned short);
  const size_t per_split_bytes = (size_t)B_ * H_ * LQ_ * (D_ + 2) * sizeof(float);
  int S = 0;
  for (int cand = 8; cand >= 1; cand >>= 1) {
    if (base_bytes + (size_t)cand * per_split_bytes <= ws_size) { S = cand; break; }
  }

  const int MQ = B_ * LQ_;         // 2048
  const int MK = B_ * LK_;         // 20000
  const int NT = (LK_ + 63) / 64;  // 157

  wtrans4<<<dim3(16, 16, 4), 256, 0, stream>>>(Wq, Wk, Wv, Wo, Wtq, Wtk, Wtv, Wto);

  proj_mfma<2, true ><<<dim3(2, 16),  256, 0, stream>>>(queries, Wtq, bq, qws, MQ);
  proj_mfma<2, false><<<dim3(2, 157), 256, 0, stream>>>(bev,     Wtk, bk, kbf, MK);
  proj_mfma<1, false><<<dim3(2, 157), 256, 0, stream>>>(bev,     Wtv, bv, vbf, MK);

  if (S <= 1) {
    attn_mfma<<<dim3(16, H_, B_), 256, 0, stream>>>(
        qws, kbf, vbf, nullptr, nullptr, nullptr, ows, NT, 1);
  } else {
    float* mpart = opart + (size_t)S * B_ * H_ * LQ_ * D_;
    float* lpart = mpart + (size_t)S * B_ * H_ * LQ_;
    const int tps = (NT + S - 1) / S;
    attn_mfma<<<dim3(16, H_, B_ * S), 256, 0, stream>>>(
        qws, kbf, vbf, opart, mpart, lpart, nullptr, tps, S);
    attn_merge<<<dim3((B_ * LQ_ * E_ + 255) / 256), 256, 0, stream>>>(
        opart, mpart, lpart, ows, S);
  }

  proj_mfma<2, true><<<dim3(2, 16), 256, 0, stream>>>(ows, Wto, bo, out, MQ);
}